// Round 1
// 358.947 us; speedup vs baseline: 11.3431x; 11.3431x over previous
//
#include <hip/hip_runtime.h>

// FFCoSTA: 15-step thermal recurrence (pbm + tiny MLP) over B=65536 elements,
// output = (32,B,13) x2 where slices 0..30 are broadcast copies of the input.
//
// R1: h[64] un-chunked -> VGPR=256 + spill, 4.8 GB scratch fetch, 4.25 ms.
// R3: __launch_bounds__(256,4) -> allocator spilled everything, 7.9 GB, WORSE.
// R4: CHUNK=16, fully-unrolled chunk loop -> STILL VGPR=256 + 4.8 GB fetch:
//     the unrolled 4-chunk MLP body is one ~1700-instr scheduling region; the
//     scheduler hoists ds_read_b128s across chunks and re-inflates pressure.
// R5 (this): pressure control, not algorithm change.
//     - CHUNK=8, chunk loop ROLLED (#pragma unroll 1, 8 iters): scheduling
//       region ~430 instrs; live set x[29]+src[13]+h[8]+scalars ~= 70 VGPR.
//       i-loop / jj-loop stay unrolled so x[]/h[]/src[] keep static indices
//       (dynamic index -> scratch, rule #20).
//     - copy branch: rolled pointer-increment store loop (was 31-deep unroll
//       with 62 live precomputed 64-bit addresses -> possible VGPR high-water).
//
// Role-split single launch (concurrent BW + compute):
//   blocks [0, CB)      : compute — 1 thread/batch elem, weights in LDS
//                         (wave-uniform broadcast ds_read, conflict-free).
//   blocks [CB, CB+CPB) : copy — float4 broadcast of T_room/T_wall into
//                         output slices 0..30, nontemporal stores.

#define STATE 13
#define HID   64
#define INDIM 29   // 2*STATE + 3
#define PRED  32
#define NSTEP 15
#define CHUNK 8    // h-tile; live regs ~ x[29]+h[8]+src[13]+scalars

typedef float vfloat4 __attribute__((ext_vector_type(4)));

constexpr int B          = 65536;
constexpr int B13        = B * STATE;            // floats per slice
constexpr int B13_4      = B13 / 4;              // float4s per slice
constexpr int CB         = B / 256;              // 256 compute blocks
constexpr int CPB        = B13_4 / 256;          // 832 copy blocks

__global__ __launch_bounds__(256) void ffcosta_kernel(
    const float* __restrict__ T_room, const float* __restrict__ T_wall,
    const float* __restrict__ T_out,  const float* __restrict__ door,
    const float* __restrict__ timing,
    const float* __restrict__ k_rw,   const float* __restrict__ k_ro,
    const float* __restrict__ k_wr,   const float* __restrict__ k_wo,
    const float* __restrict__ W1,     const float* __restrict__ b1,
    const float* __restrict__ W2,     const float* __restrict__ b2,
    float* __restrict__ out)
{
    float* out0 = out;                 // T_room_new, (32,B,13)
    float* out1 = out + PRED * B13;    // T_wall_new, (32,B,13)

    if (blockIdx.x >= CB) {
        // ---------------- copy role ----------------
        // BW-bound: rolled loop w/ pointer increments keeps this branch at
        // ~16 VGPRs so it cannot set the kernel's register high-water mark.
        const int ct = (blockIdx.x - CB) * 256 + threadIdx.x;  // [0, B13_4)
        const vfloat4 r = ((const vfloat4*)T_room)[ct];
        const vfloat4 w = ((const vfloat4*)T_wall)[ct];
        vfloat4* o0 = (vfloat4*)out0 + ct;
        vfloat4* o1 = (vfloat4*)out1 + ct;
        #pragma unroll 1
        for (int p = 0; p < PRED - 1; ++p) {
            __builtin_nontemporal_store(r, o0);
            __builtin_nontemporal_store(w, o1);
            o0 += B13_4;
            o1 += B13_4;
        }
        return;
    }

    // ---------------- compute role ----------------
    __shared__ float sW1[INDIM * HID];   // (29,64) row-major
    __shared__ float sW2[HID * 16];      // (64,13) cols padded to 16
    __shared__ float sb1[HID];
    __shared__ float sb2[16];
    __shared__ float sk[4][16];          // s * {k_rw, k_ro, k_wr, k_wo}

    const float s = 60.0f / 3600.0f;

    for (int i = threadIdx.x; i < INDIM * HID; i += 256) sW1[i] = W1[i];
    for (int j = threadIdx.x; j < HID; j += 256) {
        sb1[j] = b1[j];
        #pragma unroll
        for (int c = 0; c < 16; ++c)
            sW2[j * 16 + c] = (c < STATE) ? W2[j * STATE + c] : 0.0f;
    }
    if (threadIdx.x < 16) {
        const int c = threadIdx.x;
        sb2[c]   = (c < STATE) ? b2[c] : 0.0f;
        sk[0][c] = (c < STATE) ? s * k_rw[c] : 0.0f;
        sk[1][c] = (c < STATE) ? s * k_ro[c] : 0.0f;
        sk[2][c] = (c < STATE) ? s * k_wr[c] : 0.0f;
        sk[3][c] = (c < STATE) ? s * k_wo[c] : 0.0f;
    }
    __syncthreads();

    const int b = blockIdx.x * 256 + threadIdx.x;

    // x[] doubles as the state carrier: x[0..12]=Tr_hat, x[13..25]=Tw_hat.
    float x[INDIM];
    #pragma unroll
    for (int c = 0; c < STATE; ++c) {
        x[c]         = T_room[b * STATE + c];
        x[STATE + c] = T_wall[b * STATE + c];
    }
    const float To = T_out [b * PRED + (PRED - 1)];
    const float d  = door  [b * PRED + (PRED - 1)];
    const float t  = timing[b * PRED + (PRED - 1)];
    x[2 * STATE]     = To;
    x[2 * STATE + 1] = d;
    x[2 * STATE + 2] = t;

    const float s001 = s * 0.01f;

    #pragma unroll 1   // keep the step loop rolled
    for (int n = 0; n < NSTEP; ++n) {
        // pbm with src=0, in place: Tr,Tw (in x) -> Tr_hat,Tw_hat (in x).
        // Note Tw_next == Tw_hat exactly; Tr_next == Tr_hat + s*0.01*src_raw.
        #pragma unroll
        for (int c = 0; c < STATE; ++c) {
            const float Trc = x[c], Twc = x[STATE + c];
            const float dA = Twc - Trc;
            const float dB = To  - Trc;
            const float dC = To  - Twc;
            float trh = fmaf(dA, sk[0][c], Trc);
            trh       = fmaf(dB, sk[1][c], trh);
            float twh = fmaf(-dA, sk[2][c], Twc);
            twh       = fmaf(dC,  sk[3][c], twh);
            x[c]         = trh;
            x[STATE + c] = twh;
        }

        // fused MLP: src_raw = relu(x@W1 + b1) @ W2 + b2, h tiled by CHUNK.
        float src[STATE];
        #pragma unroll
        for (int c = 0; c < STATE; ++c) src[c] = sb2[c];

        // ROLLED chunk loop: bounds the scheduler's region so it cannot
        // hoist ds_reads across chunks and re-create the R1/R4 spill.
        #pragma unroll 1
        for (int j0 = 0; j0 < HID; j0 += CHUNK) {
            float h[CHUNK];
            #pragma unroll
            for (int jj = 0; jj < CHUNK; ++jj) h[jj] = sb1[j0 + jj];

            #pragma unroll
            for (int i = 0; i < INDIM; ++i) {
                const float xi = x[i];
                #pragma unroll
                for (int q = 0; q < CHUNK / 4; ++q) {
                    const vfloat4 w = *(const vfloat4*)&sW1[i * HID + j0 + 4 * q];
                    h[4 * q + 0] = fmaf(xi, w.x, h[4 * q + 0]);
                    h[4 * q + 1] = fmaf(xi, w.y, h[4 * q + 1]);
                    h[4 * q + 2] = fmaf(xi, w.z, h[4 * q + 2]);
                    h[4 * q + 3] = fmaf(xi, w.w, h[4 * q + 3]);
                }
            }

            #pragma unroll
            for (int jj = 0; jj < CHUNK; ++jj) {
                const float hv = fmaxf(h[jj], 0.0f);
                const float* w2 = &sW2[(j0 + jj) * 16];
                #pragma unroll
                for (int q = 0; q < 3; ++q) {
                    const vfloat4 w = *(const vfloat4*)&w2[4 * q];
                    src[4 * q + 0] = fmaf(hv, w.x, src[4 * q + 0]);
                    src[4 * q + 1] = fmaf(hv, w.y, src[4 * q + 1]);
                    src[4 * q + 2] = fmaf(hv, w.z, src[4 * q + 2]);
                }
                src[12] = fmaf(hv, w2[12], src[12]);
            }
        }

        // state update: Tr = Tr_hat + s*0.01*src_raw ; Tw = Tw_hat (in place)
        #pragma unroll
        for (int c = 0; c < STATE; ++c)
            x[c] = fmaf(src[c], s001, x[c]);
    }

    // final slice p = 31
    #pragma unroll
    for (int c = 0; c < STATE; ++c) {
        out0[(PRED - 1) * B13 + b * STATE + c] = x[c];
        out1[(PRED - 1) * B13 + b * STATE + c] = x[STATE + c];
    }
}

extern "C" void kernel_launch(void* const* d_in, const int* in_sizes, int n_in,
                              void* d_out, int out_size, void* d_ws, size_t ws_size,
                              hipStream_t stream) {
    const float* T_room = (const float*)d_in[0];
    const float* T_wall = (const float*)d_in[1];
    const float* T_out  = (const float*)d_in[2];
    const float* door   = (const float*)d_in[3];
    const float* timing = (const float*)d_in[4];
    const float* k_rw   = (const float*)d_in[5];
    const float* k_ro   = (const float*)d_in[6];
    const float* k_wr   = (const float*)d_in[7];
    const float* k_wo   = (const float*)d_in[8];
    const float* W1     = (const float*)d_in[9];
    const float* b1     = (const float*)d_in[10];
    const float* W2     = (const float*)d_in[11];
    const float* b2     = (const float*)d_in[12];
    float* out = (float*)d_out;

    ffcosta_kernel<<<CB + CPB, 256, 0, stream>>>(
        T_room, T_wall, T_out, door, timing,
        k_rw, k_ro, k_wr, k_wo, W1, b1, W2, b2, out);
}